// Round 8
// baseline (231.408 us; speedup 1.0000x reference)
//
#include <hip/hip_runtime.h>
#include <math.h>

#define BS   8192
#define DIM  256
#define KNEG 16
#define GAMMA (1.0f / 0.07f)
#define EXP_CLAMP 60.0f   // e^60*8192*16 ~ 1.5e31 < FLT_MAX: sums stay finite
#define NSTRIPS 8

typedef float v4f  __attribute__((ext_vector_type(4)));
typedef short s8b  __attribute__((ext_vector_type(8)));   // 8 bf16 as shorts

__device__ __forceinline__ float sat_exp(float dot) {
    float a = 2.0f * GAMMA * dot - 2.0f * GAMMA;
    return expf(fminf(a, EXP_CLAMP));
}

// compare-exchange: x=min, y=max (2 VALU, no selects)
__device__ __forceinline__ void ce(float& x, float& y) {
    float lo = fminf(x, y), hi = fmaxf(x, y);
    x = lo; y = hi;
}

// Batcher odd-even merge sort, 16 inputs, ascending. 63 CE = 126 VALU.
__device__ __forceinline__ void sort16(float (&a)[16]) {
    ce(a[0],a[1]); ce(a[2],a[3]); ce(a[4],a[5]); ce(a[6],a[7]);
    ce(a[8],a[9]); ce(a[10],a[11]); ce(a[12],a[13]); ce(a[14],a[15]);
    ce(a[0],a[2]); ce(a[1],a[3]); ce(a[4],a[6]); ce(a[5],a[7]);
    ce(a[8],a[10]); ce(a[9],a[11]); ce(a[12],a[14]); ce(a[13],a[15]);
    ce(a[1],a[2]); ce(a[5],a[6]); ce(a[9],a[10]); ce(a[13],a[14]);
    ce(a[0],a[4]); ce(a[1],a[5]); ce(a[2],a[6]); ce(a[3],a[7]);
    ce(a[8],a[12]); ce(a[9],a[13]); ce(a[10],a[14]); ce(a[11],a[15]);
    ce(a[2],a[4]); ce(a[3],a[5]); ce(a[10],a[12]); ce(a[11],a[13]);
    ce(a[1],a[2]); ce(a[3],a[4]); ce(a[5],a[6]);
    ce(a[9],a[10]); ce(a[11],a[12]); ce(a[13],a[14]);
    ce(a[0],a[8]); ce(a[1],a[9]); ce(a[2],a[10]); ce(a[3],a[11]);
    ce(a[4],a[12]); ce(a[5],a[13]); ce(a[6],a[14]); ce(a[7],a[15]);
    ce(a[4],a[8]); ce(a[5],a[9]); ce(a[6],a[10]); ce(a[7],a[11]);
    ce(a[2],a[4]); ce(a[3],a[5]); ce(a[6],a[8]); ce(a[7],a[9]);
    ce(a[10],a[12]); ce(a[11],a[13]);
    ce(a[1],a[2]); ce(a[3],a[4]); ce(a[5],a[6]); ce(a[7],a[8]);
    ce(a[9],a[10]); ce(a[11],a[12]); ce(a[13],a[14]);
}

// merge two ascending sorted-16, keep top-16 ascending; in place (16 max + 32 CE)
__device__ __forceinline__ void merge_top16(float (&lst)[16], const float (&nw)[16]) {
#pragma unroll
    for (int i = 0; i < 16; ++i) lst[i] = fmaxf(lst[i], nw[15 - i]);
#pragma unroll
    for (int j = 8; j > 0; j >>= 1)
#pragma unroll
        for (int i = 0; i < 16; ++i) {
            int ixj = i ^ j;
            if (ixj > i) ce(lst[i], lst[ixj]);
        }
}

// legacy insertion helper (fallback path only)
__device__ __forceinline__ void topk_insert(float (&lst)[16], float v) {
    float nl[16];
#pragma unroll
    for (int u = 0; u < 15; ++u)
        nl[u] = (v > lst[u + 1]) ? lst[u + 1] : ((v > lst[u]) ? v : lst[u]);
    nl[15] = (v > lst[15]) ? v : lst[15];
#pragma unroll
    for (int u = 0; u < 16; ++u) lst[u] = nl[u];
}

__device__ __forceinline__ unsigned short f2bf_rne(float f) {
    unsigned int u = __float_as_uint(f);
    u += 0x7FFFu + ((u >> 16) & 1u);
    return (unsigned short)(u >> 16);
}

__device__ __forceinline__ void gld_lds16(const void* g, void* l) {
    __builtin_amdgcn_global_load_lds(
        (const __attribute__((address_space(1))) void*)g,
        (__attribute__((address_space(3))) void*)l, 16, 0, 0);
}

__device__ __forceinline__ float finite_or(float x, float repl) {
    if (isnan(x)) return repl;
    if (isinf(x)) return x > 0.0f ? 3.0e38f : -3.0e38f;
    return x;
}

// ------- conv_pos: fp32 -> bf16 pre-convert + per-block diagonal partials -----
__global__ void conv_pos(const float* __restrict__ feat,
                         unsigned short* __restrict__ featbf,
                         float* __restrict__ partialPos) {
    __shared__ float red[8];
    int t = blockIdx.x * 256 + threadIdx.x;   // 0..262143
    int row = t >> 5;
    int c = t & 31;                           // 8-float chunk within the 256-dim
    const float* f1 = feat + (size_t)row * 512 + c * 8;
    const float* f2 = f1 + 256;
    float4 a0 = *(const float4*)(f1);
    float4 a1 = *(const float4*)(f1 + 4);
    float4 b0 = *(const float4*)(f2);
    float4 b1 = *(const float4*)(f2 + 4);
    uint4 pa, pb;
    pa.x = (unsigned)f2bf_rne(a0.x) | ((unsigned)f2bf_rne(a0.y) << 16);
    pa.y = (unsigned)f2bf_rne(a0.z) | ((unsigned)f2bf_rne(a0.w) << 16);
    pa.z = (unsigned)f2bf_rne(a1.x) | ((unsigned)f2bf_rne(a1.y) << 16);
    pa.w = (unsigned)f2bf_rne(a1.z) | ((unsigned)f2bf_rne(a1.w) << 16);
    pb.x = (unsigned)f2bf_rne(b0.x) | ((unsigned)f2bf_rne(b0.y) << 16);
    pb.y = (unsigned)f2bf_rne(b0.z) | ((unsigned)f2bf_rne(b0.w) << 16);
    pb.z = (unsigned)f2bf_rne(b1.x) | ((unsigned)f2bf_rne(b1.y) << 16);
    pb.w = (unsigned)f2bf_rne(b1.z) | ((unsigned)f2bf_rne(b1.w) << 16);
    *(uint4*)(featbf + (size_t)row * 512 + c * 8) = pa;
    *(uint4*)(featbf + (size_t)row * 512 + 256 + c * 8) = pb;
    float p = a0.x * b0.x + a0.y * b0.y + a0.z * b0.z + a0.w * b0.w
            + a1.x * b1.x + a1.y * b1.y + a1.z * b1.z + a1.w * b1.w;
#pragma unroll
    for (int o = 16; o; o >>= 1) p += __shfl_xor(p, o, 32);
    if (c == 0) red[threadIdx.x >> 5] = sat_exp(p);
    __syncthreads();
    if (threadIdx.x == 0) {
        float s = 0.0f;
#pragma unroll
        for (int i = 0; i < 8; ++i) s += red[i];
        partialPos[blockIdx.x] = s;
    }
}

// ---------------- stage1: barrier-free K-loop MFMA GEMM + sort-merge top-16 ---
// Block 256 thr = 4 waves. B (F1 rows, MFMA B-operand) LDS-resident for whole
// kernel (32 KB, xor-swizzled). A (F2 cols) fragments loaded per-step direct
// global->VGPR (16 B/lane, 64B-line coalesced across lane16, L2-hot).
// => NO __syncthreads in the main loop.
#define MRG_OFF 32768
#define S1_LDS  36864   // B 32 KB + merge 4 KB

__global__ __launch_bounds__(256, 4) void stage1(const unsigned short* __restrict__ featbf,
                                                 float* __restrict__ wsTop) {
    __shared__ __align__(16) char smem[S1_LDS];
    const int t = threadIdx.x;
    const int l = t & 63;
    const int w = t >> 6;
    const int wy = w >> 1, wx = w & 1;
    const int quad = l >> 4, lane16 = l & 15;
    const int nbase = blockIdx.x * 64;
    const int strip = blockIdx.y;

    // ---- stage B resident: rows nbase..nbase+63 (F1), all K, swizzled ----
#pragma unroll
    for (int jj = 0; jj < 8; ++jj) {
        int j = w * 8 + jj;
        int r = 2 * j + (l >> 5);
        int c = (l & 31) ^ (r & 31);
        gld_lds16(featbf + ((size_t)(nbase + r) << 9) + c * 8, smem + j * 1024);
    }
    __syncthreads();   // only block-wide sync until the final merge

    float lst[2][16];
#pragma unroll
    for (int ni = 0; ni < 2; ++ni)
#pragma unroll
        for (int i = 0; i < 16; ++i) lst[ni][i] = -INFINITY;

#pragma unroll 1
    for (int ct = 0; ct < 8; ++ct) {
        const int ctbase = strip * 1024 + ct * 128;
        v4f acc[4][2];
#pragma unroll
        for (int mi = 0; mi < 4; ++mi)
#pragma unroll
            for (int ni = 0; ni < 2; ++ni) acc[mi][ni] = (v4f)0.0f;

#pragma unroll
        for (int s = 0; s < 8; ++s) {
            s8b a[4];
#pragma unroll
            for (int mi = 0; mi < 4; ++mi)
                a[mi] = *(const s8b*)(featbf
                    + ((size_t)(ctbase + wx * 64 + mi * 16 + lane16) << 9)
                    + 256 + s * 32 + quad * 8);
#pragma unroll
            for (int ni = 0; ni < 2; ++ni) {
                int nl31 = ni * 16 + lane16;
                s8b b = *(const s8b*)(smem
                    + (wy * 32 + nl31) * 512 + (((s * 4 + quad) ^ nl31) & 31) * 16);
#pragma unroll
                for (int mi = 0; mi < 4; ++mi)
                    acc[mi][ni] = __builtin_amdgcn_mfma_f32_16x16x32_bf16(a[mi], b, acc[mi][ni], 0, 0, 0);
            }
        }
        // ---- batch scan: 16 fresh values per ni -> Batcher sort + merge ----
#pragma unroll
        for (int ni = 0; ni < 2; ++ni) {
            const int row = nbase + wy * 32 + ni * 16 + lane16;
            float nw[16];
#pragma unroll
            for (int mi = 0; mi < 4; ++mi) {
                const int c0 = ctbase + wx * 64 + mi * 16 + quad * 4;
#pragma unroll
                for (int r4 = 0; r4 < 4; ++r4) {
                    float v = acc[mi][ni][r4];
                    nw[mi * 4 + r4] = (c0 + r4 == row) ? -INFINITY : v;
                }
            }
            sort16(nw);
            merge_top16(lst[ni], nw);
        }
    }
    // ---- quad merge via xor-shfl (lists sorted ascending) ----
#pragma unroll
    for (int ni = 0; ni < 2; ++ni) {
#pragma unroll
        for (int r = 16; r <= 32; r <<= 1) {
            float nw[16];
#pragma unroll
            for (int i = 0; i < 16; ++i) nw[i] = __shfl(lst[ni][i], l ^ r, 64);
            merge_top16(lst[ni], nw);
        }
    }
    // ---- wx merge via LDS merge region ----
    float* mrg = (float*)(smem + MRG_OFF);   // 64 rows x 16 f32 = 4 KB
    if (wx == 1 && quad == 0) {
#pragma unroll
        for (int ni = 0; ni < 2; ++ni) {
            int rl = wy * 32 + ni * 16 + lane16;
#pragma unroll
            for (int i = 0; i < 16; i += 4)
                *(v4f*)(mrg + rl * 16 + i) = *(v4f*)&lst[ni][i];
        }
    }
    __syncthreads();
    if (wx == 0 && quad == 0) {
#pragma unroll
        for (int ni = 0; ni < 2; ++ni) {
            const int rl = wy * 32 + ni * 16 + lane16;
            float nw[16];
#pragma unroll
            for (int i = 0; i < 16; ++i) nw[i] = mrg[rl * 16 + i];
            merge_top16(lst[ni], nw);
            float* dst = wsTop + ((size_t)(nbase + rl) * NSTRIPS + strip) * 16;
#pragma unroll
            for (int i = 0; i < 16; i += 4)
                *(float4*)(dst + i) = make_float4(lst[ni][i], lst[ni][i + 1],
                                                  lst[ni][i + 2], lst[ni][i + 3]);
        }
    }
}

// ------- stage2: per-row merge of 128 candidates -> top-16 -> partial sums ----
__global__ void stage2(const float* __restrict__ wsTop, float* __restrict__ partialNeg) {
    __shared__ float red[256];
    int row = blockIdx.x * 256 + threadIdx.x;
    const float* src = wsTop + (size_t)row * (NSTRIPS * 16);
    float lst[16];
#pragma unroll
    for (int i = 0; i < 16; ++i) lst[i] = src[i];   // strip 0 list (sorted asc)
#pragma unroll 1
    for (int c = 16; c < NSTRIPS * 16; c += 16) {
        float nw[16];
#pragma unroll
        for (int i = 0; i < 16; i += 4) {
            float4 v4 = *(const float4*)(src + c + i);
            nw[i] = v4.x; nw[i + 1] = v4.y; nw[i + 2] = v4.z; nw[i + 3] = v4.w;
        }
        merge_top16(lst, nw);   // per-strip lists already sorted ascending
    }
    float s = 0.0f;
#pragma unroll
    for (int i = 0; i < 16; ++i) s += sat_exp(lst[i]);
    red[threadIdx.x] = s;
    __syncthreads();
    for (int o = 128; o; o >>= 1) {
        if (threadIdx.x < o) red[threadIdx.x] += red[threadIdx.x + o];
        __syncthreads();
    }
    if (threadIdx.x == 0) partialNeg[blockIdx.x] = red[0];
}

// ---------------- final: reduce partials, sanitize inf/nan ----------------
__global__ void final_kernel(const float* __restrict__ partialPos,
                             const float* __restrict__ partialNeg,
                             float* __restrict__ out) {
    __shared__ float w1[4], w2[4];
    float sp = 0.0f, sn = 0.0f;
    for (int i = threadIdx.x; i < 1024; i += 256) sp += partialPos[i];
    if (threadIdx.x < 32) sn = partialNeg[threadIdx.x];
#pragma unroll
    for (int o = 32; o; o >>= 1) {
        sp += __shfl_xor(sp, o, 64);
        sn += __shfl_xor(sn, o, 64);
    }
    if ((threadIdx.x & 63) == 0) {
        w1[threadIdx.x >> 6] = sp;
        w2[threadIdx.x >> 6] = sn;
    }
    __syncthreads();
    if (threadIdx.x == 0) {
        float tp = w1[0] + w1[1] + w1[2] + w1[3];
        float tn = w2[0] + w2[1] + w2[2] + w2[3];
        out[0] = finite_or(-(tp / (float)BS), 0.0f);
        out[1] = finite_or(tn / (float)(BS * KNEG), 0.0f);
    }
}

// ======================= legacy fallback (ws too small) ======================
__global__ void init_acc(float* acc) {
    if (threadIdx.x < 64) acc[threadIdx.x] = 0.0f;
}

__global__ void pos_kernel(const float* __restrict__ feat, float* __restrict__ acc) {
    int t = blockIdx.x * 256 + threadIdx.x;
    int row = t >> 4;
    int lane16 = t & 15;
    const float* f = feat + (size_t)row * 512 + lane16 * 16;
    float p = 0.0f;
#pragma unroll
    for (int q = 0; q < 16; q += 4) {
        float4 a = *(const float4*)(f + q);
        float4 b = *(const float4*)(f + 256 + q);
        p += a.x * b.x + a.y * b.y + a.z * b.z + a.w * b.w;
    }
#pragma unroll
    for (int o = 8; o; o >>= 1) p += __shfl_xor(p, o, 16);
    if (lane16 == 0) atomicAdd(&acc[0], sat_exp(p));
}

#define L_AOFF   0
#define L_BOFF   10240
#define L_PITCH  80
#define CPITCH  272
#define CWAVE   17408
#define L_SMEM  69632
__global__ __launch_bounds__(256, 2) void stage1_legacy(const float* __restrict__ feat,
                                                        float* __restrict__ wsTop) {
    __shared__ __align__(16) char smem[L_SMEM];
    const int t = threadIdx.x;
    const int l = t & 63;
    const int w = t >> 6;
    const int wy = w >> 1, wx = w & 1;
    const int quad = l >> 4, lane16 = l & 15;
    const int rowbase = blockIdx.x * 128;
    const int strip = blockIdx.y;
    char* cw = smem + w * CWAVE;
    const int grow = rowbase + wy * 64 + l;

    float lst[16];
#pragma unroll
    for (int i = 0; i < 16; ++i) lst[i] = -INFINITY;

    for (int ct = 0; ct < 4; ++ct) {
        const int colbase = strip * 1024 + ct * 256;
        v4f acc[4][8];
#pragma unroll
        for (int mi = 0; mi < 4; ++mi)
#pragma unroll
            for (int ni = 0; ni < 8; ++ni) acc[mi][ni] = (v4f)0.0f;
        for (int s = 0; s < 8; ++s) {
            const int k0 = s * 32;
            __syncthreads();
#pragma unroll
            for (int i = 0; i < 4; ++i) {
                int c = i * 256 + t;
                int r = c >> 3, chk = c & 7;
                float4 v = *(const float4*)(feat + (size_t)(rowbase + r) * 512 + k0 + chk * 4);
                uint2 pk;
                pk.x = (unsigned)f2bf_rne(v.x) | ((unsigned)f2bf_rne(v.y) << 16);
                pk.y = (unsigned)f2bf_rne(v.z) | ((unsigned)f2bf_rne(v.w) << 16);
                *(uint2*)(smem + L_AOFF + r * L_PITCH + chk * 8) = pk;
            }
#pragma unroll
            for (int i = 0; i < 8; ++i) {
                int c = i * 256 + t;
                int n = c >> 3, chk = c & 7;
                float4 v = *(const float4*)(feat + (size_t)(colbase + n) * 512 + 256 + k0 + chk * 4);
                uint2 pk;
                pk.x = (unsigned)f2bf_rne(v.x) | ((unsigned)f2bf_rne(v.y) << 16);
                pk.y = (unsigned)f2bf_rne(v.z) | ((unsigned)f2bf_rne(v.w) << 16);
                *(uint2*)(smem + L_BOFF + n * L_PITCH + chk * 8) = pk;
            }
            __syncthreads();
            s8b a[4];
#pragma unroll
            for (int mi = 0; mi < 4; ++mi)
                a[mi] = *(const s8b*)(smem + L_AOFF + (wy * 64 + mi * 16 + lane16) * L_PITCH + quad * 16);
#pragma unroll
            for (int ni = 0; ni < 8; ++ni) {
                s8b b = *(const s8b*)(smem + L_BOFF + (wx * 128 + ni * 16 + lane16) * L_PITCH + quad * 16);
#pragma unroll
                for (int mi = 0; mi < 4; ++mi)
                    acc[mi][ni] = __builtin_amdgcn_mfma_f32_16x16x32_bf16(a[mi], b, acc[mi][ni], 0, 0, 0);
            }
        }
#pragma unroll
        for (int h = 0; h < 2; ++h) {
            __syncthreads();
#pragma unroll
            for (int ni = 0; ni < 4; ++ni) {
                int c = ni * 16 + lane16;
#pragma unroll
                for (int mi = 0; mi < 4; ++mi)
                    *(v4f*)(cw + c * CPITCH + mi * 64 + quad * 16) = acc[mi][h * 4 + ni];
            }
            __syncthreads();
            const int gc0 = colbase + wx * 128 + h * 64;
            const int dj = grow - gc0;
#pragma unroll
            for (int j = 0; j < 64; ++j) {
                float v = *(const float*)(cw + j * CPITCH + l * 4);
                if (v > lst[0] && j != dj) topk_insert(lst, v);
            }
        }
    }
    float* dst = wsTop + (size_t)grow * 256 + strip * 32 + wx * 16;
#pragma unroll
    for (int i = 0; i < 16; i += 4)
        *(float4*)(dst + i) = make_float4(lst[i], lst[i + 1], lst[i + 2], lst[i + 3]);
}

__global__ void stage2_legacy(const float* __restrict__ wsTop, float* __restrict__ acc) {
    int row = blockIdx.x * blockDim.x + threadIdx.x;
    if (row >= BS) return;
    const float* src = wsTop + (size_t)row * 256;
    float lst[16];
#pragma unroll
    for (int i = 0; i < 16; ++i) lst[i] = -INFINITY;
    for (int c = 0; c < 256; c += 4) {
        float4 v4 = *(const float4*)(src + c);
        float vv[4] = {v4.x, v4.y, v4.z, v4.w};
#pragma unroll
        for (int j = 0; j < 4; ++j)
            if (vv[j] > lst[0]) topk_insert(lst, vv[j]);
    }
    float s = 0.0f;
#pragma unroll
    for (int i = 0; i < 16; ++i) s += sat_exp(lst[i]);
    atomicAdd(&acc[1], s);
}

__global__ void final_legacy(const float* __restrict__ acc, float* __restrict__ out) {
    if (threadIdx.x == 0) {
        out[0] = finite_or(-(acc[0] / (float)BS), 0.0f);
        out[1] = finite_or(acc[1] / (float)(BS * KNEG), 0.0f);
    }
}

extern "C" void kernel_launch(void* const* d_in, const int* in_sizes, int n_in,
                              void* d_out, int out_size, void* d_ws, size_t ws_size,
                              hipStream_t stream) {
    const float* feat = (const float*)d_in[0];
    float* out = (float*)d_out;

    // new path layout: featbf 8 MB | wsTop 4 MB | partialPos 4 KB | partialNeg 128 B
    unsigned short* featbf = (unsigned short*)d_ws;
    float* wsTop = (float*)(featbf + (size_t)BS * 512);
    float* partialPos = wsTop + (size_t)BS * NSTRIPS * 16;
    float* partialNeg = partialPos + 1024;
    const size_t need_new = (size_t)BS * 512 * 2 + (size_t)BS * NSTRIPS * 16 * 4
                          + (1024 + 32) * 4;

    if (ws_size >= need_new) {
        conv_pos<<<1024, 256, 0, stream>>>(feat, featbf, partialPos);
        stage1<<<dim3(128, NSTRIPS), 256, 0, stream>>>(featbf, wsTop);
        stage2<<<32, 256, 0, stream>>>(wsTop, partialNeg);
        final_kernel<<<1, 256, 0, stream>>>(partialPos, partialNeg, out);
    } else {
        float* acc = (float*)d_ws;
        float* wsTopL = acc + 64;   // 8 MB legacy layout
        init_acc<<<1, 64, 0, stream>>>(acc);
        pos_kernel<<<512, 256, 0, stream>>>(feat, acc);
        stage1_legacy<<<dim3(64, 8), 256, 0, stream>>>(feat, wsTopL);
        stage2_legacy<<<32, 256, 0, stream>>>(wsTopL, acc);
        final_legacy<<<1, 1, 0, stream>>>(acc, out);
    }
}

// Round 9
// 153.938 us; speedup vs baseline: 1.5033x; 1.5033x over previous
//
#include <hip/hip_runtime.h>
#include <math.h>

#define BS   8192
#define DIM  256
#define KNEG 16
#define GAMMA (1.0f / 0.07f)
#define EXP_CLAMP 60.0f   // e^60*8192*16 ~ 1.5e31 < FLT_MAX: sums stay finite
#define NSTRIPS 8

typedef float v4f   __attribute__((ext_vector_type(4)));
typedef float v16f  __attribute__((ext_vector_type(16)));
typedef short s8b   __attribute__((ext_vector_type(8)));   // 8 bf16 as shorts

__device__ __forceinline__ float sat_exp(float dot) {
    float a = 2.0f * GAMMA * dot - 2.0f * GAMMA;
    return expf(fminf(a, EXP_CLAMP));
}

// compare-exchange: x=min, y=max (2 VALU, no selects)
__device__ __forceinline__ void ce(float& x, float& y) {
    float lo = fminf(x, y), hi = fmaxf(x, y);
    x = lo; y = hi;
}

// Batcher odd-even merge sort, 16 inputs, ascending. 63 CE.
__device__ __forceinline__ void sort16(float (&a)[16]) {
    ce(a[0],a[1]); ce(a[2],a[3]); ce(a[4],a[5]); ce(a[6],a[7]);
    ce(a[8],a[9]); ce(a[10],a[11]); ce(a[12],a[13]); ce(a[14],a[15]);
    ce(a[0],a[2]); ce(a[1],a[3]); ce(a[4],a[6]); ce(a[5],a[7]);
    ce(a[8],a[10]); ce(a[9],a[11]); ce(a[12],a[14]); ce(a[13],a[15]);
    ce(a[1],a[2]); ce(a[5],a[6]); ce(a[9],a[10]); ce(a[13],a[14]);
    ce(a[0],a[4]); ce(a[1],a[5]); ce(a[2],a[6]); ce(a[3],a[7]);
    ce(a[8],a[12]); ce(a[9],a[13]); ce(a[10],a[14]); ce(a[11],a[15]);
    ce(a[2],a[4]); ce(a[3],a[5]); ce(a[10],a[12]); ce(a[11],a[13]);
    ce(a[1],a[2]); ce(a[3],a[4]); ce(a[5],a[6]);
    ce(a[9],a[10]); ce(a[11],a[12]); ce(a[13],a[14]);
    ce(a[0],a[8]); ce(a[1],a[9]); ce(a[2],a[10]); ce(a[3],a[11]);
    ce(a[4],a[12]); ce(a[5],a[13]); ce(a[6],a[14]); ce(a[7],a[15]);
    ce(a[4],a[8]); ce(a[5],a[9]); ce(a[6],a[10]); ce(a[7],a[11]);
    ce(a[2],a[4]); ce(a[3],a[5]); ce(a[6],a[8]); ce(a[7],a[9]);
    ce(a[10],a[12]); ce(a[11],a[13]);
    ce(a[1],a[2]); ce(a[3],a[4]); ce(a[5],a[6]); ce(a[7],a[8]);
    ce(a[9],a[10]); ce(a[11],a[12]); ce(a[13],a[14]);
}

// merge two ascending sorted-16, keep top-16 ascending (16 max + 32 CE)
__device__ __forceinline__ void merge_top16(float (&lst)[16], const float (&nw)[16]) {
#pragma unroll
    for (int i = 0; i < 16; ++i) lst[i] = fmaxf(lst[i], nw[15 - i]);
#pragma unroll
    for (int j = 8; j > 0; j >>= 1)
#pragma unroll
        for (int i = 0; i < 16; ++i) {
            int ixj = i ^ j;
            if (ixj > i) ce(lst[i], lst[ixj]);
        }
}

// legacy insertion helper (fallback path only)
__device__ __forceinline__ void topk_insert(float (&lst)[16], float v) {
    float nl[16];
#pragma unroll
    for (int u = 0; u < 15; ++u)
        nl[u] = (v > lst[u + 1]) ? lst[u + 1] : ((v > lst[u]) ? v : lst[u]);
    nl[15] = (v > lst[15]) ? v : lst[15];
#pragma unroll
    for (int u = 0; u < 16; ++u) lst[u] = nl[u];
}

__device__ __forceinline__ unsigned short f2bf_rne(float f) {
    unsigned int u = __float_as_uint(f);
    u += 0x7FFFu + ((u >> 16) & 1u);
    return (unsigned short)(u >> 16);
}

__device__ __forceinline__ void gld_lds16(const void* g, void* l) {
    __builtin_amdgcn_global_load_lds(
        (const __attribute__((address_space(1))) void*)g,
        (__attribute__((address_space(3))) void*)l, 16, 0, 0);
}

__device__ __forceinline__ float finite_or(float x, float repl) {
    if (isnan(x)) return repl;
    if (isinf(x)) return x > 0.0f ? 3.0e38f : -3.0e38f;
    return x;
}

// ------- conv_pos: fp32 -> bf16 pre-convert + per-block diagonal partials -----
__global__ void conv_pos(const float* __restrict__ feat,
                         unsigned short* __restrict__ featbf,
                         float* __restrict__ partialPos) {
    __shared__ float red[8];
    int t = blockIdx.x * 256 + threadIdx.x;   // 0..262143
    int row = t >> 5;
    int c = t & 31;                           // 8-float chunk within the 256-dim
    const float* f1 = feat + (size_t)row * 512 + c * 8;
    const float* f2 = f1 + 256;
    float4 a0 = *(const float4*)(f1);
    float4 a1 = *(const float4*)(f1 + 4);
    float4 b0 = *(const float4*)(f2);
    float4 b1 = *(const float4*)(f2 + 4);
    uint4 pa, pb;
    pa.x = (unsigned)f2bf_rne(a0.x) | ((unsigned)f2bf_rne(a0.y) << 16);
    pa.y = (unsigned)f2bf_rne(a0.z) | ((unsigned)f2bf_rne(a0.w) << 16);
    pa.z = (unsigned)f2bf_rne(a1.x) | ((unsigned)f2bf_rne(a1.y) << 16);
    pa.w = (unsigned)f2bf_rne(a1.z) | ((unsigned)f2bf_rne(a1.w) << 16);
    pb.x = (unsigned)f2bf_rne(b0.x) | ((unsigned)f2bf_rne(b0.y) << 16);
    pb.y = (unsigned)f2bf_rne(b0.z) | ((unsigned)f2bf_rne(b0.w) << 16);
    pb.z = (unsigned)f2bf_rne(b1.x) | ((unsigned)f2bf_rne(b1.y) << 16);
    pb.w = (unsigned)f2bf_rne(b1.z) | ((unsigned)f2bf_rne(b1.w) << 16);
    *(uint4*)(featbf + (size_t)row * 512 + c * 8) = pa;
    *(uint4*)(featbf + (size_t)row * 512 + 256 + c * 8) = pb;
    float p = a0.x * b0.x + a0.y * b0.y + a0.z * b0.z + a0.w * b0.w
            + a1.x * b1.x + a1.y * b1.y + a1.z * b1.z + a1.w * b1.w;
#pragma unroll
    for (int o = 16; o; o >>= 1) p += __shfl_xor(p, o, 32);
    if (c == 0) red[threadIdx.x >> 5] = sat_exp(p);
    __syncthreads();
    if (threadIdx.x == 0) {
        float s = 0.0f;
#pragma unroll
        for (int i = 0; i < 8; ++i) s += red[i];
        partialPos[blockIdx.x] = s;
    }
}

// ---------------- stage1: 32x32x16 MFMA (64x64 wave tile) + sort-merge top-16 -
// Block 256 thr = 4 waves, each wave: M=64 F2-cols x N=64 F1-rows -> 4 acc tiles
// (v16f). Block per ct: 256 M x 64 N; 4 ct per strip. B (F1) LDS-resident 32 KB;
// A staged 16 KB per s-step (BK=32) via global_load_lds. LDS 48 KB -> 3 blk/CU.
#define B_OFF  0
#define A_OFF  32768
#define S1_LDS 49152

__global__ __launch_bounds__(256, 3) void stage1(const unsigned short* __restrict__ featbf,
                                                 float* __restrict__ wsTop) {
    __shared__ __align__(16) char smem[S1_LDS];
    const int t = threadIdx.x;
    const int l = t & 63;
    const int w = t >> 6;
    const int l31 = l & 31, lh = l >> 5;
    const int nbase = blockIdx.x * 64;
    const int strip = blockIdx.y;

    // ---- stage B resident: rows nbase..nbase+63 (F1), all K, swizzled ----
#pragma unroll
    for (int jj = 0; jj < 8; ++jj) {
        int j = w * 8 + jj;
        int r = 2 * j + (l >> 5);
        int c = (l & 31) ^ (r & 31);
        gld_lds16(featbf + ((size_t)(nbase + r) << 9) + c * 8, smem + B_OFF + j * 1024);
    }
    __syncthreads();   // drain B staging

    float lst[2][16];
#pragma unroll
    for (int nt = 0; nt < 2; ++nt)
#pragma unroll
        for (int i = 0; i < 16; ++i) lst[nt][i] = -INFINITY;

#pragma unroll 1
    for (int ct = 0; ct < 4; ++ct) {
        const int ctbase = strip * 1024 + ct * 256;
        v16f acc[2][2];   // [Mtile][Ntile]
#pragma unroll
        for (int mt = 0; mt < 2; ++mt)
#pragma unroll
            for (int nt = 0; nt < 2; ++nt) acc[mt][nt] = (v16f)0.0f;

#pragma unroll
        for (int s = 0; s < 8; ++s) {
            __syncthreads();   // prev step's A frag reads done before restage
            // stage A: 256 F2-rows x 32 k = 16 KB, 4 inst/wave, rows 16/inst.
            // row pitch 64 B, slot = chunk ^ ((r>>1)&3)
#pragma unroll
            for (int jj = 0; jj < 4; ++jj) {
                int j = w * 4 + jj;
                int r = j * 16 + (l >> 2);
                int c = (l & 3) ^ ((r >> 1) & 3);
                gld_lds16(featbf + ((size_t)(ctbase + r) << 9) + 256 + s * 32 + c * 8,
                          smem + A_OFF + j * 1024);
            }
            __syncthreads();   // vmcnt(0) drain
#pragma unroll
            for (int kk = 0; kk < 2; ++kk) {
                s8b a[2], b[2];
#pragma unroll
                for (int mt = 0; mt < 2; ++mt) {
                    int r = w * 64 + mt * 32 + l31;
                    int ch = kk * 2 + lh;
                    a[mt] = *(const s8b*)(smem + A_OFF + r * 64
                              + ((ch ^ ((r >> 1) & 3)) & 3) * 16);
                }
#pragma unroll
                for (int nt = 0; nt < 2; ++nt) {
                    int n = nt * 32 + l31;
                    int c = s * 4 + kk * 2 + lh;
                    b[nt] = *(const s8b*)(smem + B_OFF + n * 512 + ((c ^ n) & 31) * 16);
                }
#pragma unroll
                for (int mt = 0; mt < 2; ++mt)
#pragma unroll
                    for (int nt = 0; nt < 2; ++nt)
                        acc[mt][nt] = __builtin_amdgcn_mfma_f32_32x32x16_bf16(
                            a[mt], b[nt], acc[mt][nt], 0, 0, 0);
            }
        }
        // ---- batch scan: per Ntile, 2x16 fresh values -> sort + merge ----
#pragma unroll
        for (int nt = 0; nt < 2; ++nt) {
            const int grow = nbase + nt * 32 + l31;
#pragma unroll
            for (int mt = 0; mt < 2; ++mt) {
                float nw[16];
#pragma unroll
                for (int j = 0; j < 16; ++j) {
                    int m = ctbase + w * 64 + mt * 32 + ((j & 3) + 8 * (j >> 2) + 4 * lh);
                    float v = acc[mt][nt][j];
                    nw[j] = (m == grow) ? -INFINITY : v;
                }
                sort16(nw);
                merge_top16(lst[nt], nw);
            }
        }
    }
    // ---- half-merge l <-> l^32 (same F1 row, different M halves) ----
#pragma unroll
    for (int nt = 0; nt < 2; ++nt) {
        float nw[16];
#pragma unroll
        for (int i = 0; i < 16; ++i) nw[i] = __shfl(lst[nt][i], l ^ 32, 64);
        merge_top16(lst[nt], nw);
    }
    // lane's own row list (avoid dynamic reg-array index -> cndmask select)
    float mine[16];
#pragma unroll
    for (int i = 0; i < 16; ++i) mine[i] = lh ? lst[1][i] : lst[0][i];

    // ---- cross-wave merge via A region (all frag reads done) ----
    __syncthreads();
    float* mrg = (float*)(smem + A_OFF);   // [3 waves][2 nt][32 lanes][16]
    if (w != 0) {
        float* dst = mrg + (((w - 1) * 2 + lh) * 32 + l31) * 16;
#pragma unroll
        for (int i = 0; i < 16; i += 4) *(v4f*)(dst + i) = *(v4f*)&mine[i];
    }
    __syncthreads();
    if (w == 0) {
#pragma unroll
        for (int ww = 0; ww < 3; ++ww) {
            float nw[16];
            const float* src = mrg + ((ww * 2 + lh) * 32 + l31) * 16;
#pragma unroll
            for (int i = 0; i < 16; ++i) nw[i] = src[i];
            merge_top16(mine, nw);
        }
        float* dst = wsTop + ((size_t)(nbase + l) * NSTRIPS + strip) * 16;
#pragma unroll
        for (int i = 0; i < 16; i += 4)
            *(float4*)(dst + i) = make_float4(mine[i], mine[i + 1], mine[i + 2], mine[i + 3]);
    }
}

// ------- stage2: 2 threads/row, merge 8 sorted lists -> top-16 -> partials ----
__global__ void stage2_fast(const float* __restrict__ wsTop, float* __restrict__ partialNeg) {
    __shared__ float red[256];
    int tid = blockIdx.x * 256 + threadIdx.x;   // 16384 threads
    int row = tid >> 1, half = tid & 1;
    const float* src = wsTop + (size_t)row * (NSTRIPS * 16) + half * 64;
    float lst[16];
#pragma unroll
    for (int i = 0; i < 16; ++i) lst[i] = src[i];
#pragma unroll
    for (int c = 16; c < 64; c += 16) {
        float nw[16];
#pragma unroll
        for (int i = 0; i < 16; ++i) nw[i] = src[c + i];
        merge_top16(lst, nw);
    }
    {   // partner merge (adjacent lane, same wave)
        float nw[16];
        int pl = (threadIdx.x & 63) ^ 1;
#pragma unroll
        for (int i = 0; i < 16; ++i) nw[i] = __shfl(lst[i], pl, 64);
        merge_top16(lst, nw);
    }
    float s = 0.0f;
#pragma unroll
    for (int i = 0; i < 16; ++i) s += sat_exp(lst[i]);
    red[threadIdx.x] = half ? 0.0f : s;
    __syncthreads();
    for (int o = 128; o; o >>= 1) {
        if (threadIdx.x < o) red[threadIdx.x] += red[threadIdx.x + o];
        __syncthreads();
    }
    if (threadIdx.x == 0) partialNeg[blockIdx.x] = red[0];
}

// ---------------- final: reduce partials, sanitize inf/nan ----------------
__global__ void final_kernel(const float* __restrict__ partialPos,
                             const float* __restrict__ partialNeg,
                             float* __restrict__ out) {
    __shared__ float w1[4], w2[4];
    float sp = 0.0f, sn = 0.0f;
    for (int i = threadIdx.x; i < 1024; i += 256) sp += partialPos[i];
    if (threadIdx.x < 64) sn = partialNeg[threadIdx.x];
#pragma unroll
    for (int o = 32; o; o >>= 1) {
        sp += __shfl_xor(sp, o, 64);
        sn += __shfl_xor(sn, o, 64);
    }
    if ((threadIdx.x & 63) == 0) {
        w1[threadIdx.x >> 6] = sp;
        w2[threadIdx.x >> 6] = sn;
    }
    __syncthreads();
    if (threadIdx.x == 0) {
        float tp = w1[0] + w1[1] + w1[2] + w1[3];
        float tn = w2[0] + w2[1] + w2[2] + w2[3];
        out[0] = finite_or(-(tp / (float)BS), 0.0f);
        out[1] = finite_or(tn / (float)(BS * KNEG), 0.0f);
    }
}

// ======================= legacy fallback (ws too small) ======================
__global__ void init_acc(float* acc) {
    if (threadIdx.x < 64) acc[threadIdx.x] = 0.0f;
}

__global__ void pos_kernel(const float* __restrict__ feat, float* __restrict__ acc) {
    int t = blockIdx.x * 256 + threadIdx.x;
    int row = t >> 4;
    int lane16 = t & 15;
    const float* f = feat + (size_t)row * 512 + lane16 * 16;
    float p = 0.0f;
#pragma unroll
    for (int q = 0; q < 16; q += 4) {
        float4 a = *(const float4*)(f + q);
        float4 b = *(const float4*)(f + 256 + q);
        p += a.x * b.x + a.y * b.y + a.z * b.z + a.w * b.w;
    }
#pragma unroll
    for (int o = 8; o; o >>= 1) p += __shfl_xor(p, o, 16);
    if (lane16 == 0) atomicAdd(&acc[0], sat_exp(p));
}

#define L_AOFF   0
#define L_BOFF   10240
#define L_PITCH  80
#define CPITCH  272
#define CWAVE   17408
#define L_SMEM  69632
__global__ __launch_bounds__(256, 2) void stage1_legacy(const float* __restrict__ feat,
                                                        float* __restrict__ wsTop) {
    __shared__ __align__(16) char smem[L_SMEM];
    const int t = threadIdx.x;
    const int l = t & 63;
    const int w = t >> 6;
    const int wy = w >> 1, wx = w & 1;
    const int quad = l >> 4, lane16 = l & 15;
    const int rowbase = blockIdx.x * 128;
    const int strip = blockIdx.y;
    char* cw = smem + w * CWAVE;
    const int grow = rowbase + wy * 64 + l;

    float lst[16];
#pragma unroll
    for (int i = 0; i < 16; ++i) lst[i] = -INFINITY;

    for (int ct = 0; ct < 4; ++ct) {
        const int colbase = strip * 1024 + ct * 256;
        v4f acc[4][8];
#pragma unroll
        for (int mi = 0; mi < 4; ++mi)
#pragma unroll
            for (int ni = 0; ni < 8; ++ni) acc[mi][ni] = (v4f)0.0f;
        for (int s = 0; s < 8; ++s) {
            const int k0 = s * 32;
            __syncthreads();
#pragma unroll
            for (int i = 0; i < 4; ++i) {
                int c = i * 256 + t;
                int r = c >> 3, chk = c & 7;
                float4 v = *(const float4*)(feat + (size_t)(rowbase + r) * 512 + k0 + chk * 4);
                uint2 pk;
                pk.x = (unsigned)f2bf_rne(v.x) | ((unsigned)f2bf_rne(v.y) << 16);
                pk.y = (unsigned)f2bf_rne(v.z) | ((unsigned)f2bf_rne(v.w) << 16);
                *(uint2*)(smem + L_AOFF + r * L_PITCH + chk * 8) = pk;
            }
#pragma unroll
            for (int i = 0; i < 8; ++i) {
                int c = i * 256 + t;
                int n = c >> 3, chk = c & 7;
                float4 v = *(const float4*)(feat + (size_t)(colbase + n) * 512 + 256 + k0 + chk * 4);
                uint2 pk;
                pk.x = (unsigned)f2bf_rne(v.x) | ((unsigned)f2bf_rne(v.y) << 16);
                pk.y = (unsigned)f2bf_rne(v.z) | ((unsigned)f2bf_rne(v.w) << 16);
                *(uint2*)(smem + L_BOFF + n * L_PITCH + chk * 8) = pk;
            }
            __syncthreads();
            s8b a[4];
#pragma unroll
            for (int mi = 0; mi < 4; ++mi)
                a[mi] = *(const s8b*)(smem + L_AOFF + (wy * 64 + mi * 16 + lane16) * L_PITCH + quad * 16);
#pragma unroll
            for (int ni = 0; ni < 8; ++ni) {
                s8b b = *(const s8b*)(smem + L_BOFF + (wx * 128 + ni * 16 + lane16) * L_PITCH + quad * 16);
#pragma unroll
                for (int mi = 0; mi < 4; ++mi)
                    acc[mi][ni] = __builtin_amdgcn_mfma_f32_16x16x32_bf16(a[mi], b, acc[mi][ni], 0, 0, 0);
            }
        }
#pragma unroll
        for (int h = 0; h < 2; ++h) {
            __syncthreads();
#pragma unroll
            for (int ni = 0; ni < 4; ++ni) {
                int c = ni * 16 + lane16;
#pragma unroll
                for (int mi = 0; mi < 4; ++mi)
                    *(v4f*)(cw + c * CPITCH + mi * 64 + quad * 16) = acc[mi][h * 4 + ni];
            }
            __syncthreads();
            const int gc0 = colbase + wx * 128 + h * 64;
            const int dj = grow - gc0;
#pragma unroll
            for (int j = 0; j < 64; ++j) {
                float v = *(const float*)(cw + j * CPITCH + l * 4);
                if (v > lst[0] && j != dj) topk_insert(lst, v);
            }
        }
    }
    float* dst = wsTop + (size_t)grow * 256 + strip * 32 + wx * 16;
#pragma unroll
    for (int i = 0; i < 16; i += 4)
        *(float4*)(dst + i) = make_float4(lst[i], lst[i + 1], lst[i + 2], lst[i + 3]);
}

__global__ void stage2_legacy(const float* __restrict__ wsTop, float* __restrict__ acc) {
    int row = blockIdx.x * blockDim.x + threadIdx.x;
    if (row >= BS) return;
    const float* src = wsTop + (size_t)row * 256;
    float lst[16];
#pragma unroll
    for (int i = 0; i < 16; ++i) lst[i] = -INFINITY;
    for (int c = 0; c < 256; c += 4) {
        float4 v4 = *(const float4*)(src + c);
        float vv[4] = {v4.x, v4.y, v4.z, v4.w};
#pragma unroll
        for (int j = 0; j < 4; ++j)
            if (vv[j] > lst[0]) topk_insert(lst, vv[j]);
    }
    float s = 0.0f;
#pragma unroll
    for (int i = 0; i < 16; ++i) s += sat_exp(lst[i]);
    atomicAdd(&acc[1], s);
}

__global__ void final_legacy(const float* __restrict__ acc, float* __restrict__ out) {
    if (threadIdx.x == 0) {
        out[0] = finite_or(-(acc[0] / (float)BS), 0.0f);
        out[1] = finite_or(acc[1] / (float)(BS * KNEG), 0.0f);
    }
}

extern "C" void kernel_launch(void* const* d_in, const int* in_sizes, int n_in,
                              void* d_out, int out_size, void* d_ws, size_t ws_size,
                              hipStream_t stream) {
    const float* feat = (const float*)d_in[0];
    float* out = (float*)d_out;

    // layout: featbf 8 MB | wsTop 4 MB | partialPos 4 KB | partialNeg 256 B
    unsigned short* featbf = (unsigned short*)d_ws;
    float* wsTop = (float*)(featbf + (size_t)BS * 512);
    float* partialPos = wsTop + (size_t)BS * NSTRIPS * 16;
    float* partialNeg = partialPos + 1024;
    const size_t need_new = (size_t)BS * 512 * 2 + (size_t)BS * NSTRIPS * 16 * 4
                          + (1024 + 64) * 4;

    if (ws_size >= need_new) {
        conv_pos<<<1024, 256, 0, stream>>>(feat, featbf, partialPos);
        stage1<<<dim3(128, NSTRIPS), 256, 0, stream>>>(featbf, wsTop);
        stage2_fast<<<64, 256, 0, stream>>>(wsTop, partialNeg);
        final_kernel<<<1, 256, 0, stream>>>(partialPos, partialNeg, out);
    } else {
        float* acc = (float*)d_ws;
        float* wsTopL = acc + 64;   // 8 MB legacy layout
        init_acc<<<1, 64, 0, stream>>>(acc);
        pos_kernel<<<512, 256, 0, stream>>>(feat, acc);
        stage1_legacy<<<dim3(64, 8), 256, 0, stream>>>(feat, wsTopL);
        stage2_legacy<<<32, 256, 0, stream>>>(wsTopL, acc);
        final_legacy<<<1, 1, 0, stream>>>(acc, out);
    }
}

// Round 10
// 147.201 us; speedup vs baseline: 1.5721x; 1.0458x over previous
//
#include <hip/hip_runtime.h>
#include <math.h>

#define BS   8192
#define DIM  256
#define KNEG 16
#define GAMMA (1.0f / 0.07f)
#define EXP_CLAMP 60.0f   // e^60*8192*16 ~ 1.5e31 < FLT_MAX: sums stay finite
#define NSTRIPS 8

typedef float v4f  __attribute__((ext_vector_type(4)));
typedef short s8b  __attribute__((ext_vector_type(8)));   // 8 bf16 as shorts

__device__ __forceinline__ float sat_exp(float dot) {
    float a = 2.0f * GAMMA * dot - 2.0f * GAMMA;
    return expf(fminf(a, EXP_CLAMP));
}

// compare-exchange: x=min, y=max (2 VALU, no selects)
__device__ __forceinline__ void ce(float& x, float& y) {
    float lo = fminf(x, y), hi = fmaxf(x, y);
    x = lo; y = hi;
}

// Batcher odd-even merge sort, 16 inputs, ascending. 63 CE.
__device__ __forceinline__ void sort16(float (&a)[16]) {
    ce(a[0],a[1]); ce(a[2],a[3]); ce(a[4],a[5]); ce(a[6],a[7]);
    ce(a[8],a[9]); ce(a[10],a[11]); ce(a[12],a[13]); ce(a[14],a[15]);
    ce(a[0],a[2]); ce(a[1],a[3]); ce(a[4],a[6]); ce(a[5],a[7]);
    ce(a[8],a[10]); ce(a[9],a[11]); ce(a[12],a[14]); ce(a[13],a[15]);
    ce(a[1],a[2]); ce(a[5],a[6]); ce(a[9],a[10]); ce(a[13],a[14]);
    ce(a[0],a[4]); ce(a[1],a[5]); ce(a[2],a[6]); ce(a[3],a[7]);
    ce(a[8],a[12]); ce(a[9],a[13]); ce(a[10],a[14]); ce(a[11],a[15]);
    ce(a[2],a[4]); ce(a[3],a[5]); ce(a[10],a[12]); ce(a[11],a[13]);
    ce(a[1],a[2]); ce(a[3],a[4]); ce(a[5],a[6]);
    ce(a[9],a[10]); ce(a[11],a[12]); ce(a[13],a[14]);
    ce(a[0],a[8]); ce(a[1],a[9]); ce(a[2],a[10]); ce(a[3],a[11]);
    ce(a[4],a[12]); ce(a[5],a[13]); ce(a[6],a[14]); ce(a[7],a[15]);
    ce(a[4],a[8]); ce(a[5],a[9]); ce(a[6],a[10]); ce(a[7],a[11]);
    ce(a[2],a[4]); ce(a[3],a[5]); ce(a[6],a[8]); ce(a[7],a[9]);
    ce(a[10],a[12]); ce(a[11],a[13]);
    ce(a[1],a[2]); ce(a[3],a[4]); ce(a[5],a[6]); ce(a[7],a[8]);
    ce(a[9],a[10]); ce(a[11],a[12]); ce(a[13],a[14]);
}

// merge two ascending sorted-16, keep top-16 ascending (16 max + 32 CE)
__device__ __forceinline__ void merge_top16(float (&lst)[16], const float (&nw)[16]) {
#pragma unroll
    for (int i = 0; i < 16; ++i) lst[i] = fmaxf(lst[i], nw[15 - i]);
#pragma unroll
    for (int j = 8; j > 0; j >>= 1)
#pragma unroll
        for (int i = 0; i < 16; ++i) {
            int ixj = i ^ j;
            if (ixj > i) ce(lst[i], lst[ixj]);
        }
}

// legacy insertion helper (fallback path only)
__device__ __forceinline__ void topk_insert(float (&lst)[16], float v) {
    float nl[16];
#pragma unroll
    for (int u = 0; u < 15; ++u)
        nl[u] = (v > lst[u + 1]) ? lst[u + 1] : ((v > lst[u]) ? v : lst[u]);
    nl[15] = (v > lst[15]) ? v : lst[15];
#pragma unroll
    for (int u = 0; u < 16; ++u) lst[u] = nl[u];
}

__device__ __forceinline__ unsigned short f2bf_rne(float f) {
    unsigned int u = __float_as_uint(f);
    u += 0x7FFFu + ((u >> 16) & 1u);
    return (unsigned short)(u >> 16);
}

__device__ __forceinline__ void gld_lds16(const void* g, void* l) {
    __builtin_amdgcn_global_load_lds(
        (const __attribute__((address_space(1))) void*)g,
        (__attribute__((address_space(3))) void*)l, 16, 0, 0);
}

__device__ __forceinline__ float finite_or(float x, float repl) {
    if (isnan(x)) return repl;
    if (isinf(x)) return x > 0.0f ? 3.0e38f : -3.0e38f;
    return x;
}

// ------- conv_pos: fp32 -> bf16 pre-convert + per-block diagonal partials -----
__global__ void conv_pos(const float* __restrict__ feat,
                         unsigned short* __restrict__ featbf,
                         float* __restrict__ partialPos) {
    __shared__ float red[8];
    int t = blockIdx.x * 256 + threadIdx.x;   // 0..262143
    int row = t >> 5;
    int c = t & 31;                           // 8-float chunk within the 256-dim
    const float* f1 = feat + (size_t)row * 512 + c * 8;
    const float* f2 = f1 + 256;
    float4 a0 = *(const float4*)(f1);
    float4 a1 = *(const float4*)(f1 + 4);
    float4 b0 = *(const float4*)(f2);
    float4 b1 = *(const float4*)(f2 + 4);
    uint4 pa, pb;
    pa.x = (unsigned)f2bf_rne(a0.x) | ((unsigned)f2bf_rne(a0.y) << 16);
    pa.y = (unsigned)f2bf_rne(a0.z) | ((unsigned)f2bf_rne(a0.w) << 16);
    pa.z = (unsigned)f2bf_rne(a1.x) | ((unsigned)f2bf_rne(a1.y) << 16);
    pa.w = (unsigned)f2bf_rne(a1.z) | ((unsigned)f2bf_rne(a1.w) << 16);
    pb.x = (unsigned)f2bf_rne(b0.x) | ((unsigned)f2bf_rne(b0.y) << 16);
    pb.y = (unsigned)f2bf_rne(b0.z) | ((unsigned)f2bf_rne(b0.w) << 16);
    pb.z = (unsigned)f2bf_rne(b1.x) | ((unsigned)f2bf_rne(b1.y) << 16);
    pb.w = (unsigned)f2bf_rne(b1.z) | ((unsigned)f2bf_rne(b1.w) << 16);
    *(uint4*)(featbf + (size_t)row * 512 + c * 8) = pa;
    *(uint4*)(featbf + (size_t)row * 512 + 256 + c * 8) = pb;
    float p = a0.x * b0.x + a0.y * b0.y + a0.z * b0.z + a0.w * b0.w
            + a1.x * b1.x + a1.y * b1.y + a1.z * b1.z + a1.w * b1.w;
#pragma unroll
    for (int o = 16; o; o >>= 1) p += __shfl_xor(p, o, 32);
    if (c == 0) red[threadIdx.x >> 5] = sat_exp(p);
    __syncthreads();
    if (threadIdx.x == 0) {
        float s = 0.0f;
#pragma unroll
        for (int i = 0; i < 8; ++i) s += red[i];
        partialPos[blockIdx.x] = s;
    }
}

// ---------------- stage1: R7 structure + reg-resident B + pipelined A dbuf ----
// Block 256 thr = 4 waves (wy=row-half, wx=col-half). 16x16x32 MFMA.
// Phase 1: B (64 F1 rows x K=256) staged to LDS (32 KB, swizzled), then ALL
//          B-frags hoisted to registers (breg[8][2], 64 VGPR) -> LDS freed.
// Phase 2: A (F2 cols) double-buffered in the freed region: 2 x 16 KB (BK=64),
//          one barrier per 64-k chunk, prefetch issued right after the barrier
//          so the next barrier's vmcnt drain is already satisfied.
// Scan: per-ct register sort-merge top-16 (R7, validated).
#define S1_LDS 32768

__global__ __launch_bounds__(256, 3) void stage1(const unsigned short* __restrict__ featbf,
                                                 float* __restrict__ wsTop) {
    __shared__ __align__(16) char smem[S1_LDS];
    const int t = threadIdx.x;
    const int l = t & 63;
    const int w = t >> 6;
    const int wy = w >> 1, wx = w & 1;
    const int quad = l >> 4, lane16 = l & 15;
    const int key7 = lane16 & 7;              // A frag swizzle key (row&7)
    const int nbase = blockIdx.x * 64;
    const int strip = blockIdx.y;

    // ---- Phase 1a: stage B resident (rows nbase.., all K, xor-swizzled) ----
#pragma unroll
    for (int jj = 0; jj < 8; ++jj) {
        int j = w * 8 + jj;
        int r = 2 * j + (l >> 5);
        int c = (l & 31) ^ (r & 31);
        gld_lds16(featbf + ((size_t)(nbase + r) << 9) + c * 8, smem + j * 1024);
    }
    __syncthreads();   // B staging visible

    // ---- Phase 1b: hoist all B-fragments to registers (64 VGPR) ----
    s8b breg[8][2];
#pragma unroll
    for (int s = 0; s < 8; ++s)
#pragma unroll
        for (int ni = 0; ni < 2; ++ni) {
            int n31 = ni * 16 + lane16;
            breg[s][ni] = *(const s8b*)(smem + (wy * 32 + n31) * 512
                                        + (((s * 4 + quad) ^ n31) & 31) * 16);
        }
    __syncthreads();   // all waves done reading B -> LDS reusable for A

    float lst[2][16];
#pragma unroll
    for (int ni = 0; ni < 2; ++ni)
#pragma unroll
        for (int i = 0; i < 16; ++i) lst[ni][i] = -INFINITY;

    v4f acc[4][2];
#pragma unroll
    for (int mi = 0; mi < 4; ++mi)
#pragma unroll
        for (int ni = 0; ni < 2; ++ni) acc[mi][ni] = (v4f)0.0f;

    // A staging helper values: 16 insts (4/wave), 8 rows x 128 B each
    const int sj_r = (l >> 3);                // row within 8-row group
    const int sj_c = (l & 7);                 // slot within 128-B row

    // initial prefetch: ct=0, h=0 -> buf0
    {
        const int ctbase = strip * 1024;
#pragma unroll
        for (int jj = 0; jj < 4; ++jj) {
            int j = w * 4 + jj;
            int r = 8 * j + sj_r;
            int c = sj_c ^ (r & 7);
            gld_lds16(featbf + ((size_t)(ctbase + r) << 9) + 256 + c * 8,
                      smem + j * 1024);
        }
    }

#pragma unroll 1
    for (int ct = 0; ct < 8; ++ct) {
        const int ctbase = strip * 1024 + ct * 128;
#pragma unroll
        for (int h = 0; h < 4; ++h) {
            __syncthreads();   // drains prefetch issued one phase ago; protects dbuf swap
            // prefetch next chunk into the other buffer
            if (h < 3 || ct < 7) {
                const int nct = (h == 3) ? ctbase + 128 : ctbase;
                const int nh = (h == 3) ? 0 : h + 1;
                const int nbuf = ((h + 1) & 1) * 16384;
#pragma unroll
                for (int jj = 0; jj < 4; ++jj) {
                    int j = w * 4 + jj;
                    int r = 8 * j + sj_r;
                    int c = sj_c ^ (r & 7);
                    gld_lds16(featbf + ((size_t)(nct + r) << 9) + 256 + nh * 64 + c * 8,
                              smem + nbuf + j * 1024);
                }
            }
            // compute current chunk (64 k = 2 MFMA k-steps)
            const char* Ab = smem + (h & 1) * 16384;
#pragma unroll
            for (int kh = 0; kh < 2; ++kh) {
                const int s = h * 2 + kh;     // compile-time per (h,kh)
                s8b a[4];
#pragma unroll
                for (int mi = 0; mi < 4; ++mi) {
                    int ra = wx * 64 + mi * 16 + lane16;
                    a[mi] = *(const s8b*)(Ab + ra * 128
                              + (((kh * 4 + quad) ^ key7) & 7) * 16);
                }
#pragma unroll
                for (int ni = 0; ni < 2; ++ni)
#pragma unroll
                    for (int mi = 0; mi < 4; ++mi)
                        acc[mi][ni] = __builtin_amdgcn_mfma_f32_16x16x32_bf16(
                            a[mi], breg[s][ni], acc[mi][ni], 0, 0, 0);
            }
        }
        // ---- batch scan: 16 fresh values per ni -> Batcher sort + merge ----
#pragma unroll
        for (int ni = 0; ni < 2; ++ni) {
            const int row = nbase + wy * 32 + ni * 16 + lane16;
            float nw[16];
#pragma unroll
            for (int mi = 0; mi < 4; ++mi) {
                const int c0 = ctbase + wx * 64 + mi * 16 + quad * 4;
#pragma unroll
                for (int r4 = 0; r4 < 4; ++r4) {
                    float v = acc[mi][ni][r4];
                    nw[mi * 4 + r4] = (c0 + r4 == row) ? -INFINITY : v;
                }
            }
            sort16(nw);
            merge_top16(lst[ni], nw);
#pragma unroll
            for (int mi = 0; mi < 4; ++mi) acc[mi][ni] = (v4f)0.0f;
        }
    }
    // ---- quad merge via xor-shfl (lists sorted ascending) ----
#pragma unroll
    for (int ni = 0; ni < 2; ++ni) {
#pragma unroll
        for (int r = 16; r <= 32; r <<= 1) {
            float nw[16];
#pragma unroll
            for (int i = 0; i < 16; ++i) nw[i] = __shfl(lst[ni][i], l ^ r, 64);
            merge_top16(lst[ni], nw);
        }
    }
    // ---- wx merge via LDS (buffers free) ----
    float* mrg = (float*)smem;   // 64 rows x 16 f32 = 4 KB
    if (wx == 1 && quad == 0) {
#pragma unroll
        for (int ni = 0; ni < 2; ++ni) {
            int rl = wy * 32 + ni * 16 + lane16;
#pragma unroll
            for (int i = 0; i < 16; i += 4)
                *(v4f*)(mrg + rl * 16 + i) = *(v4f*)&lst[ni][i];
        }
    }
    __syncthreads();
    if (wx == 0 && quad == 0) {
#pragma unroll
        for (int ni = 0; ni < 2; ++ni) {
            const int rl = wy * 32 + ni * 16 + lane16;
            float nw[16];
#pragma unroll
            for (int i = 0; i < 16; ++i) nw[i] = mrg[rl * 16 + i];
            merge_top16(lst[ni], nw);
            float* dst = wsTop + ((size_t)(nbase + rl) * NSTRIPS + strip) * 16;
#pragma unroll
            for (int i = 0; i < 16; i += 4)
                *(float4*)(dst + i) = make_float4(lst[ni][i], lst[ni][i + 1],
                                                  lst[ni][i + 2], lst[ni][i + 3]);
        }
    }
}

// ------- stage2: 2 threads/row, merge 8 sorted lists -> top-16 -> partials ----
__global__ void stage2_fast(const float* __restrict__ wsTop, float* __restrict__ partialNeg) {
    __shared__ float red[128];
    int tid = blockIdx.x * 128 + threadIdx.x;   // 16384 threads, 128 blocks
    int row = tid >> 1, half = tid & 1;
    const float* src = wsTop + (size_t)row * (NSTRIPS * 16) + half * 64;
    float lst[16];
#pragma unroll
    for (int i = 0; i < 16; ++i) lst[i] = src[i];
#pragma unroll
    for (int c = 16; c < 64; c += 16) {
        float nw[16];
#pragma unroll
        for (int i = 0; i < 16; ++i) nw[i] = src[c + i];
        merge_top16(lst, nw);
    }
    {   // partner merge (adjacent lane, same wave)
        float nw[16];
        int pl = (threadIdx.x & 63) ^ 1;
#pragma unroll
        for (int i = 0; i < 16; ++i) nw[i] = __shfl(lst[i], pl, 64);
        merge_top16(lst, nw);
    }
    float s = 0.0f;
#pragma unroll
    for (int i = 0; i < 16; ++i) s += sat_exp(lst[i]);
    red[threadIdx.x] = half ? 0.0f : s;
    __syncthreads();
    for (int o = 64; o; o >>= 1) {
        if (threadIdx.x < o) red[threadIdx.x] += red[threadIdx.x + o];
        __syncthreads();
    }
    if (threadIdx.x == 0) partialNeg[blockIdx.x] = red[0];
}

// ---------------- final: reduce partials, sanitize inf/nan ----------------
__global__ void final_kernel(const float* __restrict__ partialPos,
                             const float* __restrict__ partialNeg,
                             float* __restrict__ out) {
    __shared__ float w1[4], w2[4];
    float sp = 0.0f, sn = 0.0f;
    for (int i = threadIdx.x; i < 1024; i += 256) sp += partialPos[i];
    if (threadIdx.x < 128) sn = partialNeg[threadIdx.x];
#pragma unroll
    for (int o = 32; o; o >>= 1) {
        sp += __shfl_xor(sp, o, 64);
        sn += __shfl_xor(sn, o, 64);
    }
    if ((threadIdx.x & 63) == 0) {
        w1[threadIdx.x >> 6] = sp;
        w2[threadIdx.x >> 6] = sn;
    }
    __syncthreads();
    if (threadIdx.x == 0) {
        float tp = w1[0] + w1[1] + w1[2] + w1[3];
        float tn = w2[0] + w2[1] + w2[2] + w2[3];
        out[0] = finite_or(-(tp / (float)BS), 0.0f);
        out[1] = finite_or(tn / (float)(BS * KNEG), 0.0f);
    }
}

// ======================= legacy fallback (ws too small) ======================
__global__ void init_acc(float* acc) {
    if (threadIdx.x < 64) acc[threadIdx.x] = 0.0f;
}

__global__ void pos_kernel(const float* __restrict__ feat, float* __restrict__ acc) {
    int t = blockIdx.x * 256 + threadIdx.x;
    int row = t >> 4;
    int lane16 = t & 15;
    const float* f = feat + (size_t)row * 512 + lane16 * 16;
    float p = 0.0f;
#pragma unroll
    for (int q = 0; q < 16; q += 4) {
        float4 a = *(const float4*)(f + q);
        float4 b = *(const float4*)(f + 256 + q);
        p += a.x * b.x + a.y * b.y + a.z * b.z + a.w * b.w;
    }
#pragma unroll
    for (int o = 8; o; o >>= 1) p += __shfl_xor(p, o, 16);
    if (lane16 == 0) atomicAdd(&acc[0], sat_exp(p));
}

#define L_AOFF   0
#define L_BOFF   10240
#define L_PITCH  80
#define CPITCH  272
#define CWAVE   17408
#define L_SMEM  69632
__global__ __launch_bounds__(256, 2) void stage1_legacy(const float* __restrict__ feat,
                                                        float* __restrict__ wsTop) {
    __shared__ __align__(16) char smem[L_SMEM];
    const int t = threadIdx.x;
    const int l = t & 63;
    const int w = t >> 6;
    const int wy = w >> 1, wx = w & 1;
    const int quad = l >> 4, lane16 = l & 15;
    const int rowbase = blockIdx.x * 128;
    const int strip = blockIdx.y;
    char* cw = smem + w * CWAVE;
    const int grow = rowbase + wy * 64 + l;

    float lst[16];
#pragma unroll
    for (int i = 0; i < 16; ++i) lst[i] = -INFINITY;

    for (int ct = 0; ct < 4; ++ct) {
        const int colbase = strip * 1024 + ct * 256;
        v4f acc[4][8];
#pragma unroll
        for (int mi = 0; mi < 4; ++mi)
#pragma unroll
            for (int ni = 0; ni < 8; ++ni) acc[mi][ni] = (v4f)0.0f;
        for (int s = 0; s < 8; ++s) {
            const int k0 = s * 32;
            __syncthreads();
#pragma unroll
            for (int i = 0; i < 4; ++i) {
                int c = i * 256 + t;
                int r = c >> 3, chk = c & 7;
                float4 v = *(const float4*)(feat + (size_t)(rowbase + r) * 512 + k0 + chk * 4);
                uint2 pk;
                pk.x = (unsigned)f2bf_rne(v.x) | ((unsigned)f2bf_rne(v.y) << 16);
                pk.y = (unsigned)f2bf_rne(v.z) | ((unsigned)f2bf_rne(v.w) << 16);
                *(uint2*)(smem + L_AOFF + r * L_PITCH + chk * 8) = pk;
            }
#pragma unroll
            for (int i = 0; i < 8; ++i) {
                int c = i * 256 + t;
                int n = c >> 3, chk = c & 7;
                float4 v = *(const float4*)(feat + (size_t)(colbase + n) * 512 + 256 + k0 + chk * 4);
                uint2 pk;
                pk.x = (unsigned)f2bf_rne(v.x) | ((unsigned)f2bf_rne(v.y) << 16);
                pk.y = (unsigned)f2bf_rne(v.z) | ((unsigned)f2bf_rne(v.w) << 16);
                *(uint2*)(smem + L_BOFF + n * L_PITCH + chk * 8) = pk;
            }
            __syncthreads();
            s8b a[4];
#pragma unroll
            for (int mi = 0; mi < 4; ++mi)
                a[mi] = *(const s8b*)(smem + L_AOFF + (wy * 64 + mi * 16 + lane16) * L_PITCH + quad * 16);
#pragma unroll
            for (int ni = 0; ni < 8; ++ni) {
                s8b b = *(const s8b*)(smem + L_BOFF + (wx * 128 + ni * 16 + lane16) * L_PITCH + quad * 16);
#pragma unroll
                for (int mi = 0; mi < 4; ++mi)
                    acc[mi][ni] = __builtin_amdgcn_mfma_f32_16x16x32_bf16(a[mi], b, acc[mi][ni], 0, 0, 0);
            }
        }
#pragma unroll
        for (int h = 0; h < 2; ++h) {
            __syncthreads();
#pragma unroll
            for (int ni = 0; ni < 4; ++ni) {
                int c = ni * 16 + lane16;
#pragma unroll
                for (int mi = 0; mi < 4; ++mi)
                    *(v4f*)(cw + c * CPITCH + mi * 64 + quad * 16) = acc[mi][h * 4 + ni];
            }
            __syncthreads();
            const int gc0 = colbase + wx * 128 + h * 64;
            const int dj = grow - gc0;
#pragma unroll
            for (int j = 0; j < 64; ++j) {
                float v = *(const float*)(cw + j * CPITCH + l * 4);
                if (v > lst[0] && j != dj) topk_insert(lst, v);
            }
        }
    }
    float* dst = wsTop + (size_t)grow * 256 + strip * 32 + wx * 16;
#pragma unroll
    for (int i = 0; i < 16; i += 4)
        *(float4*)(dst + i) = make_float4(lst[i], lst[i + 1], lst[i + 2], lst[i + 3]);
}

__global__ void stage2_legacy(const float* __restrict__ wsTop, float* __restrict__ acc) {
    int row = blockIdx.x * blockDim.x + threadIdx.x;
    if (row >= BS) return;
    const float* src = wsTop + (size_t)row * 256;
    float lst[16];
#pragma unroll
    for (int i = 0; i < 16; ++i) lst[i] = -INFINITY;
    for (int c = 0; c < 256; c += 4) {
        float4 v4 = *(const float4*)(src + c);
        float vv[4] = {v4.x, v4.y, v4.z, v4.w};
#pragma unroll
        for (int j = 0; j < 4; ++j)
            if (vv[j] > lst[0]) topk_insert(lst, vv[j]);
    }
    float s = 0.0f;
#pragma unroll
    for (int i = 0; i < 16; ++i) s += sat_exp(lst[i]);
    atomicAdd(&acc[1], s);
}

__global__ void final_legacy(const float* __restrict__ acc, float* __restrict__ out) {
    if (threadIdx.x == 0) {
        out[0] = finite_or(-(acc[0] / (float)BS), 0.0f);
        out[1] = finite_or(acc[1] / (float)(BS * KNEG), 0.0f);
    }
}

extern "C" void kernel_launch(void* const* d_in, const int* in_sizes, int n_in,
                              void* d_out, int out_size, void* d_ws, size_t ws_size,
                              hipStream_t stream) {
    const float* feat = (const float*)d_in[0];
    float* out = (float*)d_out;

    // layout: featbf 8 MB | wsTop 4 MB | partialPos 4 KB | partialNeg 512 B
    unsigned short* featbf = (unsigned short*)d_ws;
    float* wsTop = (float*)(featbf + (size_t)BS * 512);
    float* partialPos = wsTop + (size_t)BS * NSTRIPS * 16;
    float* partialNeg = partialPos + 1024;
    const size_t need_new = (size_t)BS * 512 * 2 + (size_t)BS * NSTRIPS * 16 * 4
                          + (1024 + 128) * 4;

    if (ws_size >= need_new) {
        conv_pos<<<1024, 256, 0, stream>>>(feat, featbf, partialPos);
        stage1<<<dim3(128, NSTRIPS), 256, 0, stream>>>(featbf, wsTop);
        stage2_fast<<<128, 128, 0, stream>>>(wsTop, partialNeg);
        final_kernel<<<1, 256, 0, stream>>>(partialPos, partialNeg, out);
    } else {
        float* acc = (float*)d_ws;
        float* wsTopL = acc + 64;   // 8 MB legacy layout
        init_acc<<<1, 64, 0, stream>>>(acc);
        pos_kernel<<<512, 256, 0, stream>>>(feat, acc);
        stage1_legacy<<<dim3(64, 8), 256, 0, stream>>>(feat, wsTopL);
        stage2_legacy<<<32, 256, 0, stream>>>(wsTopL, acc);
        final_legacy<<<1, 1, 0, stream>>>(acc, out);
    }
}

// Round 11
// 135.461 us; speedup vs baseline: 1.7083x; 1.0867x over previous
//
#include <hip/hip_runtime.h>
#include <math.h>

#define BS   8192
#define DIM  256
#define KNEG 16
#define GAMMA (1.0f / 0.07f)
#define EXP_CLAMP 60.0f   // e^60*8192*16 ~ 1.5e31 < FLT_MAX: sums stay finite
#define NSTRIPS 8

typedef float v4f  __attribute__((ext_vector_type(4)));
typedef short s8b  __attribute__((ext_vector_type(8)));   // 8 bf16 as shorts

__device__ __forceinline__ float sat_exp(float dot) {
    float a = 2.0f * GAMMA * dot - 2.0f * GAMMA;
    return expf(fminf(a, EXP_CLAMP));
}

// compare-exchange: x=min, y=max (2 VALU, no selects)
__device__ __forceinline__ void ce(float& x, float& y) {
    float lo = fminf(x, y), hi = fmaxf(x, y);
    x = lo; y = hi;
}

// Batcher odd-even merge sort, 16 inputs, ascending. 63 CE.
__device__ __forceinline__ void sort16(float (&a)[16]) {
    ce(a[0],a[1]); ce(a[2],a[3]); ce(a[4],a[5]); ce(a[6],a[7]);
    ce(a[8],a[9]); ce(a[10],a[11]); ce(a[12],a[13]); ce(a[14],a[15]);
    ce(a[0],a[2]); ce(a[1],a[3]); ce(a[4],a[6]); ce(a[5],a[7]);
    ce(a[8],a[10]); ce(a[9],a[11]); ce(a[12],a[14]); ce(a[13],a[15]);
    ce(a[1],a[2]); ce(a[5],a[6]); ce(a[9],a[10]); ce(a[13],a[14]);
    ce(a[0],a[4]); ce(a[1],a[5]); ce(a[2],a[6]); ce(a[3],a[7]);
    ce(a[8],a[12]); ce(a[9],a[13]); ce(a[10],a[14]); ce(a[11],a[15]);
    ce(a[2],a[4]); ce(a[3],a[5]); ce(a[10],a[12]); ce(a[11],a[13]);
    ce(a[1],a[2]); ce(a[3],a[4]); ce(a[5],a[6]);
    ce(a[9],a[10]); ce(a[11],a[12]); ce(a[13],a[14]);
    ce(a[0],a[8]); ce(a[1],a[9]); ce(a[2],a[10]); ce(a[3],a[11]);
    ce(a[4],a[12]); ce(a[5],a[13]); ce(a[6],a[14]); ce(a[7],a[15]);
    ce(a[4],a[8]); ce(a[5],a[9]); ce(a[6],a[10]); ce(a[7],a[11]);
    ce(a[2],a[4]); ce(a[3],a[5]); ce(a[6],a[8]); ce(a[7],a[9]);
    ce(a[10],a[12]); ce(a[11],a[13]);
    ce(a[1],a[2]); ce(a[3],a[4]); ce(a[5],a[6]); ce(a[7],a[8]);
    ce(a[9],a[10]); ce(a[11],a[12]); ce(a[13],a[14]);
}

// merge two ascending sorted-16, keep top-16 ascending (16 max + 32 CE)
__device__ __forceinline__ void merge_top16(float (&lst)[16], const float (&nw)[16]) {
#pragma unroll
    for (int i = 0; i < 16; ++i) lst[i] = fmaxf(lst[i], nw[15 - i]);
#pragma unroll
    for (int j = 8; j > 0; j >>= 1)
#pragma unroll
        for (int i = 0; i < 16; ++i) {
            int ixj = i ^ j;
            if (ixj > i) ce(lst[i], lst[ixj]);
        }
}

// legacy insertion helper (fallback path only)
__device__ __forceinline__ void topk_insert(float (&lst)[16], float v) {
    float nl[16];
#pragma unroll
    for (int u = 0; u < 15; ++u)
        nl[u] = (v > lst[u + 1]) ? lst[u + 1] : ((v > lst[u]) ? v : lst[u]);
    nl[15] = (v > lst[15]) ? v : lst[15];
#pragma unroll
    for (int u = 0; u < 16; ++u) lst[u] = nl[u];
}

__device__ __forceinline__ unsigned short f2bf_rne(float f) {
    unsigned int u = __float_as_uint(f);
    u += 0x7FFFu + ((u >> 16) & 1u);
    return (unsigned short)(u >> 16);
}

__device__ __forceinline__ void gld_lds16(const void* g, void* l) {
    __builtin_amdgcn_global_load_lds(
        (const __attribute__((address_space(1))) void*)g,
        (__attribute__((address_space(3))) void*)l, 16, 0, 0);
}

__device__ __forceinline__ float finite_or(float x, float repl) {
    if (isnan(x)) return repl;
    if (isinf(x)) return x > 0.0f ? 3.0e38f : -3.0e38f;
    return x;
}

// ------- conv_pos: fp32 -> bf16 pre-convert + per-block diagonal partials -----
__global__ void conv_pos(const float* __restrict__ feat,
                         unsigned short* __restrict__ featbf,
                         float* __restrict__ partialPos) {
    __shared__ float red[8];
    int t = blockIdx.x * 256 + threadIdx.x;   // 0..262143
    int row = t >> 5;
    int c = t & 31;                           // 8-float chunk within the 256-dim
    const float* f1 = feat + (size_t)row * 512 + c * 8;
    const float* f2 = f1 + 256;
    float4 a0 = *(const float4*)(f1);
    float4 a1 = *(const float4*)(f1 + 4);
    float4 b0 = *(const float4*)(f2);
    float4 b1 = *(const float4*)(f2 + 4);
    uint4 pa, pb;
    pa.x = (unsigned)f2bf_rne(a0.x) | ((unsigned)f2bf_rne(a0.y) << 16);
    pa.y = (unsigned)f2bf_rne(a0.z) | ((unsigned)f2bf_rne(a0.w) << 16);
    pa.z = (unsigned)f2bf_rne(a1.x) | ((unsigned)f2bf_rne(a1.y) << 16);
    pa.w = (unsigned)f2bf_rne(a1.z) | ((unsigned)f2bf_rne(a1.w) << 16);
    pb.x = (unsigned)f2bf_rne(b0.x) | ((unsigned)f2bf_rne(b0.y) << 16);
    pb.y = (unsigned)f2bf_rne(b0.z) | ((unsigned)f2bf_rne(b0.w) << 16);
    pb.z = (unsigned)f2bf_rne(b1.x) | ((unsigned)f2bf_rne(b1.y) << 16);
    pb.w = (unsigned)f2bf_rne(b1.z) | ((unsigned)f2bf_rne(b1.w) << 16);
    *(uint4*)(featbf + (size_t)row * 512 + c * 8) = pa;
    *(uint4*)(featbf + (size_t)row * 512 + 256 + c * 8) = pb;
    float p = a0.x * b0.x + a0.y * b0.y + a0.z * b0.z + a0.w * b0.w
            + a1.x * b1.x + a1.y * b1.y + a1.z * b1.z + a1.w * b1.w;
#pragma unroll
    for (int o = 16; o; o >>= 1) p += __shfl_xor(p, o, 32);
    if (c == 0) red[threadIdx.x >> 5] = sat_exp(p);
    __syncthreads();
    if (threadIdx.x == 0) {
        float s = 0.0f;
#pragma unroll
        for (int i = 0; i < 8; ++i) s += red[i];
        partialPos[blockIdx.x] = s;
    }
}

// ---------------- stage1: R7 compute/scan + single-barrier A double-buffer ----
// Block 256 thr = 4 waves (wy=row-half, wx=col-half). 16x16x32 MFMA.
// B (64 F1 rows x K=256) LDS-resident 32 KB (xor-swizzled), read per-step as
// fragments (NO persistent register hoist -- that spilled in R9/R10).
// A (128 F2 cols x BK=32) double-buffered 2x8 KB: per k-step
//   barrier -> issue prefetch(next)->buf^1 -> compute buf.
// Buffer parity = s&1 (compile-time). One barrier per k-step; its vmcnt drain
// waits on loads issued a full compute phase earlier.
#define A_OFF  32768
#define S1_LDS 49152

__global__ __launch_bounds__(256, 3) void stage1(const unsigned short* __restrict__ featbf,
                                                 float* __restrict__ wsTop) {
    __shared__ __align__(16) char smem[S1_LDS];
    const int t = threadIdx.x;
    const int l = t & 63;
    const int w = t >> 6;
    const int wy = w >> 1, wx = w & 1;
    const int quad = l >> 4, lane16 = l & 15;
    const int nbase = blockIdx.x * 64;
    const int strip = blockIdx.y;

    // ---- stage B resident: rows nbase..nbase+63 (F1), all K, swizzled ----
#pragma unroll
    for (int jj = 0; jj < 8; ++jj) {
        int j = w * 8 + jj;
        int r = 2 * j + (l >> 5);
        int c = (l & 31) ^ (r & 31);
        gld_lds16(featbf + ((size_t)(nbase + r) << 9) + c * 8, smem + j * 1024);
    }

    float lst[2][16];
#pragma unroll
    for (int ni = 0; ni < 2; ++ni)
#pragma unroll
        for (int i = 0; i < 16; ++i) lst[ni][i] = -INFINITY;

    const int akey = (quad ^ ((lane16 >> 1) & 3)) * 16;   // A frag slot offset
    // A staging lane roles: inst j covers 16 rows; lane l -> row 16j+(l>>2),
    // slot l&3, content chunk c = (l&3) ^ ((r>>1)&3). Row pitch 64 B.
    const int sj_r = l >> 2;
    const int sj_s = l & 3;

    // initial prefetch: ct=0, s=0 -> buf0 (B staging still in flight; fine)
    {
        const int ctbase = strip * 1024;
#pragma unroll
        for (int jj = 0; jj < 2; ++jj) {
            int j = w * 2 + jj;
            int r = 16 * j + sj_r;
            int c = sj_s ^ ((r >> 1) & 3);
            gld_lds16(featbf + ((size_t)(ctbase + r) << 9) + 256 + c * 8,
                      smem + A_OFF + j * 1024);
        }
    }

#pragma unroll 1
    for (int ct = 0; ct < 8; ++ct) {
        const int ctbase = strip * 1024 + ct * 128;
        v4f acc[4][2];
#pragma unroll
        for (int mi = 0; mi < 4; ++mi)
#pragma unroll
            for (int ni = 0; ni < 2; ++ni) acc[mi][ni] = (v4f)0.0f;

#pragma unroll
        for (int s = 0; s < 8; ++s) {
            __syncthreads();   // drains prefetch for THIS step (issued a full phase ago)
            // prefetch next k-chunk into the other buffer
            if (ct < 7 || s < 7) {
                const int nct = (s == 7) ? ctbase + 128 : ctbase;
                const int ns = (s == 7) ? 0 : s + 1;
                char* dst = smem + A_OFF + ((s + 1) & 1) * 8192;
#pragma unroll
                for (int jj = 0; jj < 2; ++jj) {
                    int j = w * 2 + jj;
                    int r = 16 * j + sj_r;
                    int c = sj_s ^ ((r >> 1) & 3);
                    gld_lds16(featbf + ((size_t)(nct + r) << 9) + 256 + ns * 32 + c * 8,
                              dst + j * 1024);
                }
            }
            // compute current chunk
            const char* Ab = smem + A_OFF + (s & 1) * 8192;
            s8b a[4];
#pragma unroll
            for (int mi = 0; mi < 4; ++mi)
                a[mi] = *(const s8b*)(Ab + (wx * 64 + mi * 16 + lane16) * 64 + akey);
#pragma unroll
            for (int ni = 0; ni < 2; ++ni) {
                int n31 = ni * 16 + lane16;
                s8b b = *(const s8b*)(smem
                    + (wy * 32 + n31) * 512 + (((s * 4 + quad) ^ n31) & 31) * 16);
#pragma unroll
                for (int mi = 0; mi < 4; ++mi)
                    acc[mi][ni] = __builtin_amdgcn_mfma_f32_16x16x32_bf16(
                        a[mi], b, acc[mi][ni], 0, 0, 0);
            }
        }
        // ---- batch scan: 16 fresh values per ni -> Batcher sort + merge ----
#pragma unroll
        for (int ni = 0; ni < 2; ++ni) {
            const int row = nbase + wy * 32 + ni * 16 + lane16;
            float nw[16];
#pragma unroll
            for (int mi = 0; mi < 4; ++mi) {
                const int c0 = ctbase + wx * 64 + mi * 16 + quad * 4;
#pragma unroll
                for (int r4 = 0; r4 < 4; ++r4) {
                    float v = acc[mi][ni][r4];
                    nw[mi * 4 + r4] = (c0 + r4 == row) ? -INFINITY : v;
                }
            }
            sort16(nw);
            merge_top16(lst[ni], nw);
        }
    }
    // ---- quad merge via xor-shfl (lists sorted ascending) ----
#pragma unroll
    for (int ni = 0; ni < 2; ++ni) {
#pragma unroll
        for (int r = 16; r <= 32; r <<= 1) {
            float nw[16];
#pragma unroll
            for (int i = 0; i < 16; ++i) nw[i] = __shfl(lst[ni][i], l ^ r, 64);
            merge_top16(lst[ni], nw);
        }
    }
    // ---- wx merge via LDS (A buffers idle: last prefetch consumed) ----
    __syncthreads();
    float* mrg = (float*)(smem + A_OFF);   // 64 rows x 16 f32 = 4 KB
    if (wx == 1 && quad == 0) {
#pragma unroll
        for (int ni = 0; ni < 2; ++ni) {
            int rl = wy * 32 + ni * 16 + lane16;
#pragma unroll
            for (int i = 0; i < 16; i += 4)
                *(v4f*)(mrg + rl * 16 + i) = *(v4f*)&lst[ni][i];
        }
    }
    __syncthreads();
    if (wx == 0 && quad == 0) {
#pragma unroll
        for (int ni = 0; ni < 2; ++ni) {
            const int rl = wy * 32 + ni * 16 + lane16;
            float nw[16];
#pragma unroll
            for (int i = 0; i < 16; ++i) nw[i] = mrg[rl * 16 + i];
            merge_top16(lst[ni], nw);
            float* dst = wsTop + ((size_t)(nbase + rl) * NSTRIPS + strip) * 16;
#pragma unroll
            for (int i = 0; i < 16; i += 4)
                *(float4*)(dst + i) = make_float4(lst[ni][i], lst[ni][i + 1],
                                                  lst[ni][i + 2], lst[ni][i + 3]);
        }
    }
}

// ------- stage2: 2 threads/row, merge 8 sorted lists -> top-16 -> partials ----
__global__ void stage2_fast(const float* __restrict__ wsTop, float* __restrict__ partialNeg) {
    __shared__ float red[128];
    int tid = blockIdx.x * 128 + threadIdx.x;   // 16384 threads, 128 blocks
    int row = tid >> 1, half = tid & 1;
    const float* src = wsTop + (size_t)row * (NSTRIPS * 16) + half * 64;
    float lst[16];
#pragma unroll
    for (int i = 0; i < 16; ++i) lst[i] = src[i];
#pragma unroll
    for (int c = 16; c < 64; c += 16) {
        float nw[16];
#pragma unroll
        for (int i = 0; i < 16; ++i) nw[i] = src[c + i];
        merge_top16(lst, nw);
    }
    {   // partner merge (adjacent lane, same wave)
        float nw[16];
        int pl = (threadIdx.x & 63) ^ 1;
#pragma unroll
        for (int i = 0; i < 16; ++i) nw[i] = __shfl(lst[i], pl, 64);
        merge_top16(lst, nw);
    }
    float s = 0.0f;
#pragma unroll
    for (int i = 0; i < 16; ++i) s += sat_exp(lst[i]);
    red[threadIdx.x] = half ? 0.0f : s;
    __syncthreads();
    for (int o = 64; o; o >>= 1) {
        if (threadIdx.x < o) red[threadIdx.x] += red[threadIdx.x + o];
        __syncthreads();
    }
    if (threadIdx.x == 0) partialNeg[blockIdx.x] = red[0];
}

// ---------------- final: reduce partials, sanitize inf/nan ----------------
__global__ void final_kernel(const float* __restrict__ partialPos,
                             const float* __restrict__ partialNeg,
                             float* __restrict__ out) {
    __shared__ float w1[4], w2[4];
    float sp = 0.0f, sn = 0.0f;
    for (int i = threadIdx.x; i < 1024; i += 256) sp += partialPos[i];
    if (threadIdx.x < 128) sn = partialNeg[threadIdx.x];
#pragma unroll
    for (int o = 32; o; o >>= 1) {
        sp += __shfl_xor(sp, o, 64);
        sn += __shfl_xor(sn, o, 64);
    }
    if ((threadIdx.x & 63) == 0) {
        w1[threadIdx.x >> 6] = sp;
        w2[threadIdx.x >> 6] = sn;
    }
    __syncthreads();
    if (threadIdx.x == 0) {
        float tp = w1[0] + w1[1] + w1[2] + w1[3];
        float tn = w2[0] + w2[1] + w2[2] + w2[3];
        out[0] = finite_or(-(tp / (float)BS), 0.0f);
        out[1] = finite_or(tn / (float)(BS * KNEG), 0.0f);
    }
}

// ======================= legacy fallback (ws too small) ======================
__global__ void init_acc(float* acc) {
    if (threadIdx.x < 64) acc[threadIdx.x] = 0.0f;
}

__global__ void pos_kernel(const float* __restrict__ feat, float* __restrict__ acc) {
    int t = blockIdx.x * 256 + threadIdx.x;
    int row = t >> 4;
    int lane16 = t & 15;
    const float* f = feat + (size_t)row * 512 + lane16 * 16;
    float p = 0.0f;
#pragma unroll
    for (int q = 0; q < 16; q += 4) {
        float4 a = *(const float4*)(f + q);
        float4 b = *(const float4*)(f + 256 + q);
        p += a.x * b.x + a.y * b.y + a.z * b.z + a.w * b.w;
    }
#pragma unroll
    for (int o = 8; o; o >>= 1) p += __shfl_xor(p, o, 16);
    if (lane16 == 0) atomicAdd(&acc[0], sat_exp(p));
}

#define L_AOFF   0
#define L_BOFF   10240
#define L_PITCH  80
#define CPITCH  272
#define CWAVE   17408
#define L_SMEM  69632
__global__ __launch_bounds__(256, 2) void stage1_legacy(const float* __restrict__ feat,
                                                        float* __restrict__ wsTop) {
    __shared__ __align__(16) char smem[L_SMEM];
    const int t = threadIdx.x;
    const int l = t & 63;
    const int w = t >> 6;
    const int wy = w >> 1, wx = w & 1;
    const int quad = l >> 4, lane16 = l & 15;
    const int rowbase = blockIdx.x * 128;
    const int strip = blockIdx.y;
    char* cw = smem + w * CWAVE;
    const int grow = rowbase + wy * 64 + l;

    float lst[16];
#pragma unroll
    for (int i = 0; i < 16; ++i) lst[i] = -INFINITY;

    for (int ct = 0; ct < 4; ++ct) {
        const int colbase = strip * 1024 + ct * 256;
        v4f acc[4][8];
#pragma unroll
        for (int mi = 0; mi < 4; ++mi)
#pragma unroll
            for (int ni = 0; ni < 8; ++ni) acc[mi][ni] = (v4f)0.0f;
        for (int s = 0; s < 8; ++s) {
            const int k0 = s * 32;
            __syncthreads();
#pragma unroll
            for (int i = 0; i < 4; ++i) {
                int c = i * 256 + t;
                int r = c >> 3, chk = c & 7;
                float4 v = *(const float4*)(feat + (size_t)(rowbase + r) * 512 + k0 + chk * 4);
                uint2 pk;
                pk.x = (unsigned)f2bf_rne(v.x) | ((unsigned)f2bf_rne(v.y) << 16);
                pk.y = (unsigned)f2bf_rne(v.z) | ((unsigned)f2bf_rne(v.w) << 16);
                *(uint2*)(smem + L_AOFF + r * L_PITCH + chk * 8) = pk;
            }
#pragma unroll
            for (int i = 0; i < 8; ++i) {
                int c = i * 256 + t;
                int n = c >> 3, chk = c & 7;
                float4 v = *(const float4*)(feat + (size_t)(colbase + n) * 512 + 256 + k0 + chk * 4);
                uint2 pk;
                pk.x = (unsigned)f2bf_rne(v.x) | ((unsigned)f2bf_rne(v.y) << 16);
                pk.y = (unsigned)f2bf_rne(v.z) | ((unsigned)f2bf_rne(v.w) << 16);
                *(uint2*)(smem + L_BOFF + n * L_PITCH + chk * 8) = pk;
            }
            __syncthreads();
            s8b a[4];
#pragma unroll
            for (int mi = 0; mi < 4; ++mi)
                a[mi] = *(const s8b*)(smem + L_AOFF + (wy * 64 + mi * 16 + lane16) * L_PITCH + quad * 16);
#pragma unroll
            for (int ni = 0; ni < 8; ++ni) {
                s8b b = *(const s8b*)(smem + L_BOFF + (wx * 128 + ni * 16 + lane16) * L_PITCH + quad * 16);
#pragma unroll
                for (int mi = 0; mi < 4; ++mi)
                    acc[mi][ni] = __builtin_amdgcn_mfma_f32_16x16x32_bf16(a[mi], b, acc[mi][ni], 0, 0, 0);
            }
        }
#pragma unroll
        for (int h = 0; h < 2; ++h) {
            __syncthreads();
#pragma unroll
            for (int ni = 0; ni < 4; ++ni) {
                int c = ni * 16 + lane16;
#pragma unroll
                for (int mi = 0; mi < 4; ++mi)
                    *(v4f*)(cw + c * CPITCH + mi * 64 + quad * 16) = acc[mi][h * 4 + ni];
            }
            __syncthreads();
            const int gc0 = colbase + wx * 128 + h * 64;
            const int dj = grow - gc0;
#pragma unroll
            for (int j = 0; j < 64; ++j) {
                float v = *(const float*)(cw + j * CPITCH + l * 4);
                if (v > lst[0] && j != dj) topk_insert(lst, v);
            }
        }
    }
    float* dst = wsTop + (size_t)grow * 256 + strip * 32 + wx * 16;
#pragma unroll
    for (int i = 0; i < 16; i += 4)
        *(float4*)(dst + i) = make_float4(lst[i], lst[i + 1], lst[i + 2], lst[i + 3]);
}

__global__ void stage2_legacy(const float* __restrict__ wsTop, float* __restrict__ acc) {
    int row = blockIdx.x * blockDim.x + threadIdx.x;
    if (row >= BS) return;
    const float* src = wsTop + (size_t)row * 256;
    float lst[16];
#pragma unroll
    for (int i = 0; i < 16; ++i) lst[i] = -INFINITY;
    for (int c = 0; c < 256; c += 4) {
        float4 v4 = *(const float4*)(src + c);
        float vv[4] = {v4.x, v4.y, v4.z, v4.w};
#pragma unroll
        for (int j = 0; j < 4; ++j)
            if (vv[j] > lst[0]) topk_insert(lst, vv[j]);
    }
    float s = 0.0f;
#pragma unroll
    for (int i = 0; i < 16; ++i) s += sat_exp(lst[i]);
    atomicAdd(&acc[1], s);
}

__global__ void final_legacy(const float* __restrict__ acc, float* __restrict__ out) {
    if (threadIdx.x == 0) {
        out[0] = finite_or(-(acc[0] / (float)BS), 0.0f);
        out[1] = finite_or(acc[1] / (float)(BS * KNEG), 0.0f);
    }
}

extern "C" void kernel_launch(void* const* d_in, const int* in_sizes, int n_in,
                              void* d_out, int out_size, void* d_ws, size_t ws_size,
                              hipStream_t stream) {
    const float* feat = (const float*)d_in[0];
    float* out = (float*)d_out;

    // layout: featbf 8 MB | wsTop 4 MB | partialPos 4 KB | partialNeg 512 B
    unsigned short* featbf = (unsigned short*)d_ws;
    float* wsTop = (float*)(featbf + (size_t)BS * 512);
    float* partialPos = wsTop + (size_t)BS * NSTRIPS * 16;
    float* partialNeg = partialPos + 1024;
    const size_t need_new = (size_t)BS * 512 * 2 + (size_t)BS * NSTRIPS * 16 * 4
                          + (1024 + 128) * 4;

    if (ws_size >= need_new) {
        conv_pos<<<1024, 256, 0, stream>>>(feat, featbf, partialPos);
        stage1<<<dim3(128, NSTRIPS), 256, 0, stream>>>(featbf, wsTop);
        stage2_fast<<<128, 128, 0, stream>>>(wsTop, partialNeg);
        final_kernel<<<1, 256, 0, stream>>>(partialPos, partialNeg, out);
    } else {
        float* acc = (float*)d_ws;
        float* wsTopL = acc + 64;   // 8 MB legacy layout
        init_acc<<<1, 64, 0, stream>>>(acc);
        pos_kernel<<<512, 256, 0, stream>>>(feat, acc);
        stage1_legacy<<<dim3(64, 8), 256, 0, stream>>>(feat, wsTopL);
        stage2_legacy<<<32, 256, 0, stream>>>(wsTopL, acc);
        final_legacy<<<1, 1, 0, stream>>>(acc, out);
    }
}